// Round 4
// baseline (498.098 us; speedup 1.0000x reference)
//
#include <hip/hip_runtime.h>

#define S_LEN  2048
#define HIDDEN 512
#define NHEAD  8
#define DHEAD  64
#define NSEL   256
#define ROWS_A 8
#define SCALE_ 0.125f

// intra-wave LDS producer->consumer sync (lockstep lanes + drain LDS queue)
#define WAVE_SYNC() __asm__ volatile("s_waitcnt lgkmcnt(0)" ::: "memory")

// monotone float->uint mapping (ascending float == ascending uint)
__device__ __forceinline__ unsigned mapu(float f) {
  unsigned u = __float_as_uint(f);
  return (u & 0x80000000u) ? ~u : (u | 0x80000000u);
}

// C[m][n] = sum_k A[m][k] * B[n][k]   (A: MxK, B: NxK, row-major)
__global__ __launch_bounds__(256) void gemm_nt(const float* __restrict__ A,
                                               const float* __restrict__ B,
                                               float* __restrict__ C,
                                               int M, int N, int K) {
  __shared__ float As[32][68];   // [k][m]
  __shared__ float Bs[32][68];   // [k][n]
  const int m0 = blockIdx.x * 64, n0 = blockIdx.y * 64;
  const int t  = threadIdx.x;
  const int tx = t & 15, ty = t >> 4;
  float acc[4][4] = {};
  for (int k0 = 0; k0 < K; k0 += 32) {
    __syncthreads();
#pragma unroll
    for (int s = 0; s < 2; ++s) {
      int slot = t + s * 256;
      int r = slot >> 3, c = (slot & 7) << 2;
      const float4 fa = *(const float4*)&A[(size_t)(m0 + r) * K + k0 + c];
      As[c + 0][r] = fa.x; As[c + 1][r] = fa.y; As[c + 2][r] = fa.z; As[c + 3][r] = fa.w;
      const float4 fb = *(const float4*)&B[(size_t)(n0 + r) * K + k0 + c];
      Bs[c + 0][r] = fb.x; Bs[c + 1][r] = fb.y; Bs[c + 2][r] = fb.z; Bs[c + 3][r] = fb.w;
    }
    __syncthreads();
#pragma unroll
    for (int kk = 0; kk < 32; ++kk) {
      const float4 a4 = *(const float4*)&As[kk][ty * 4];
      const float4 b4 = *(const float4*)&Bs[kk][tx * 4];
      const float a[4] = {a4.x, a4.y, a4.z, a4.w};
      const float b[4] = {b4.x, b4.y, b4.z, b4.w};
#pragma unroll
      for (int i = 0; i < 4; ++i)
#pragma unroll
        for (int j = 0; j < 4; ++j) acc[i][j] += a[i] * b[j];
    }
  }
#pragma unroll
  for (int i = 0; i < 4; ++i) {
    float4 o = make_float4(acc[i][0], acc[i][1], acc[i][2], acc[i][3]);
    *(float4*)&C[(size_t)(m0 + ty * 4 + i) * N + n0 + tx * 4] = o;
  }
}

// Fused importance+score GEMM. Tile 128q x 64k, full depth 64.
// sd[h*S+q][k] = { mapu(dot_{d<32}), bits(dot_{d<64} * SCALE) }  (uint2, coalesced)
// importance contraction order identical to validated imp_gemm -> same selection bits.
__global__ __launch_bounds__(256) void score_gemm(const float* __restrict__ Q,
                                                  const float* __restrict__ K,
                                                  uint2* __restrict__ sd) {
  __shared__ float Qs[64][132];   // [d][q], 33.8 KB
  __shared__ float Ks[64][68];    // [d][k], 17.4 KB
  const int bid  = blockIdx.x;
  const int h    = bid & (NHEAD - 1);
  const int tile = bid >> 3;
  const int q0   = (tile & 15) * 128;   // 16 q-tiles
  const int k0   = (tile >> 4) * 64;    // 32 k-tiles
  const int t  = threadIdx.x;
  const int tx = t & 15, ty = t >> 4;   // tx: 4 k-cols, ty: 8 q-rows

  // stage Q tile: 128x64 floats, 8 float4/thread
#pragma unroll
  for (int s = 0; s < 8; ++s) {
    const int sf = s * 256 + t;
    const int r = sf >> 4, c = (sf & 15) * 4;
    const float4 f = *(const float4*)&Q[(size_t)(q0 + r) * HIDDEN + h * DHEAD + c];
    Qs[c + 0][r] = f.x; Qs[c + 1][r] = f.y; Qs[c + 2][r] = f.z; Qs[c + 3][r] = f.w;
  }
  // stage K tile: 64x64 floats, 4 float4/thread
#pragma unroll
  for (int s = 0; s < 4; ++s) {
    const int sf = s * 256 + t;
    const int r = sf >> 4, c = (sf & 15) * 4;
    const float4 f = *(const float4*)&K[(size_t)(k0 + r) * HIDDEN + h * DHEAD + c];
    Ks[c + 0][r] = f.x; Ks[c + 1][r] = f.y; Ks[c + 2][r] = f.z; Ks[c + 3][r] = f.w;
  }
  __syncthreads();

  float acc[8][4] = {};
#pragma unroll
  for (int d = 0; d < 32; ++d) {
    const float4 aa = *(const float4*)&Qs[d][ty * 8];
    const float4 ab = *(const float4*)&Qs[d][ty * 8 + 4];
    const float4 b4 = *(const float4*)&Ks[d][tx * 4];
    const float a[8] = {aa.x, aa.y, aa.z, aa.w, ab.x, ab.y, ab.z, ab.w};
    const float b[4] = {b4.x, b4.y, b4.z, b4.w};
#pragma unroll
    for (int i = 0; i < 8; ++i)
#pragma unroll
      for (int j = 0; j < 4; ++j) acc[i][j] += a[i] * b[j];
  }
  float simp[8][4];
#pragma unroll
  for (int i = 0; i < 8; ++i)
#pragma unroll
    for (int j = 0; j < 4; ++j) simp[i][j] = acc[i][j];   // importance snapshot (d<32)
#pragma unroll
  for (int d = 32; d < 64; ++d) {
    const float4 aa = *(const float4*)&Qs[d][ty * 8];
    const float4 ab = *(const float4*)&Qs[d][ty * 8 + 4];
    const float4 b4 = *(const float4*)&Ks[d][tx * 4];
    const float a[8] = {aa.x, aa.y, aa.z, aa.w, ab.x, ab.y, ab.z, ab.w};
    const float b[4] = {b4.x, b4.y, b4.z, b4.w};
#pragma unroll
    for (int i = 0; i < 8; ++i)
#pragma unroll
      for (int j = 0; j < 4; ++j) acc[i][j] += a[i] * b[j];
  }

#pragma unroll
  for (int i = 0; i < 8; ++i) {
    const size_t gr = (size_t)(h * S_LEN) + q0 + ty * 8 + i;
    uint4* rowp = (uint4*)(sd + gr * S_LEN);   // 2 uint2 per uint4
    const uint4 w0 = make_uint4(mapu(simp[i][0]), __float_as_uint(acc[i][0] * SCALE_),
                                mapu(simp[i][1]), __float_as_uint(acc[i][1] * SCALE_));
    const uint4 w1 = make_uint4(mapu(simp[i][2]), __float_as_uint(acc[i][2] * SCALE_),
                                mapu(simp[i][3]), __float_as_uint(acc[i][3] * SCALE_));
    rowp[(k0 >> 1) + tx * 2 + 0] = w0;
    rowp[(k0 >> 1) + tx * 2 + 1] = w1;
  }
}

// One wave per row. Row's 2048 {imp,score} pairs -> 16 uint4/lane (registers).
// Radix top-256 on imp, softmax on in-register scores, PV gather, AO write.
// Zero scattered reads; V rows read wave-contiguous (256B).
__global__ __launch_bounds__(512) void fused_select_pv(const uint2* __restrict__ sd,
                                                       const float* __restrict__ V,
                                                       float* __restrict__ AO) {
  __shared__ unsigned hist[ROWS_A][256];           // 8 KB
  __shared__ float    sbuf[ROWS_A][NSEL];          // 8 KB
  __shared__ unsigned short ibuf[ROWS_A][NSEL];    // 4 KB
  __shared__ unsigned short eqbuf[ROWS_A][64];     // 1 KB
  __shared__ unsigned cnt[ROWS_A], eqcnt[ROWS_A];
  __shared__ unsigned rstate[ROWS_A][2];

  const int t = threadIdx.x, wv = t >> 6, lane = t & 63;
  const size_t gr = (size_t)blockIdx.x * ROWS_A + wv;   // gr = h*S + q
  const uint4* rp = (const uint4*)sd + gr * (S_LEN / 2);

  uint4 u[16];
#pragma unroll
  for (int j = 0; j < 16; ++j) u[j] = rp[j * 64 + lane];
  // element ids: u[j] -> {2*(j*64+lane), 2*(j*64+lane)+1}; .x/.z = imp, .y/.w = score bits

  // ---- exact top-256 threshold: 4-round byte radix on imp (registers) ----
  unsigned prefix = 0, krem = NSEL;
#pragma unroll 1
  for (int b = 3; b >= 0; --b) {
    hist[wv][lane] = 0; hist[wv][lane + 64] = 0; hist[wv][lane + 128] = 0; hist[wv][lane + 192] = 0;
    WAVE_SYNC();
    const int shift = b * 8;
#pragma unroll
    for (int j = 0; j < 16; ++j) {
      const unsigned v0 = u[j].x, v1 = u[j].z;
      if ((b == 3) || ((v0 >> (shift + 8)) == prefix)) atomicAdd(&hist[wv][(v0 >> shift) & 0xFF], 1u);
      if ((b == 3) || ((v1 >> (shift + 8)) == prefix)) atomicAdd(&hist[wv][(v1 >> shift) & 0xFF], 1u);
    }
    WAVE_SYNC();
    const int g = 63 - lane;
    const uint4 c4 = *(const uint4*)&hist[wv][4 * g];
    const unsigned c0 = c4.x, c1 = c4.y, c2 = c4.z, c3 = c4.w;
    const unsigned lsum = c0 + c1 + c2 + c3;
    unsigned incl = lsum;
#pragma unroll
    for (int off = 1; off < 64; off <<= 1) {
      unsigned o = __shfl_up(incl, off);
      if (lane >= off) incl += o;
    }
    const unsigned excl = incl - lsum;
    const unsigned ab3 = excl, ab2 = excl + c3, ab1 = excl + c3 + c2, ab0 = excl + c3 + c2 + c1;
    if (ab3 < krem && krem <= ab3 + c3) { rstate[wv][0] = 4u*g+3u; rstate[wv][1] = krem - ab3; }
    if (ab2 < krem && krem <= ab2 + c2) { rstate[wv][0] = 4u*g+2u; rstate[wv][1] = krem - ab2; }
    if (ab1 < krem && krem <= ab1 + c1) { rstate[wv][0] = 4u*g+1u; rstate[wv][1] = krem - ab1; }
    if (ab0 < krem && krem <= ab0 + c0) { rstate[wv][0] = 4u*g+0u; rstate[wv][1] = krem - ab0; }
    WAVE_SYNC();
    prefix = (prefix << 8) | rstate[wv][0];
    krem   = rstate[wv][1];
  }
  const unsigned T = prefix;

  // ---- collect selected (idx, score) into LDS ----
  if (lane == 0) { cnt[wv] = 0; eqcnt[wv] = 0; }
  WAVE_SYNC();
#pragma unroll
  for (int j = 0; j < 16; ++j) {
    const int e0 = (j * 64 + lane) * 2;
    const unsigned v0 = u[j].x, v1 = u[j].z;
    if (v0 > T)       { unsigned p = atomicAdd(&cnt[wv], 1u);   ibuf[wv][p] = (unsigned short)e0; sbuf[wv][p] = __uint_as_float(u[j].y); }
    else if (v0 == T) { unsigned p = atomicAdd(&eqcnt[wv], 1u); if (p < 64) eqbuf[wv][p] = (unsigned short)e0; }
    if (v1 > T)       { unsigned p = atomicAdd(&cnt[wv], 1u);   ibuf[wv][p] = (unsigned short)(e0 + 1); sbuf[wv][p] = __uint_as_float(u[j].w); }
    else if (v1 == T) { unsigned p = atomicAdd(&eqcnt[wv], 1u); if (p < 64) eqbuf[wv][p] = (unsigned short)(e0 + 1); }
  }
  WAVE_SYNC();
  const unsigned ngt = cnt[wv], ne = eqcnt[wv];
  const unsigned need = NSEL - ngt;
  const uint2* row2 = sd + gr * S_LEN;
  if (ne == need && ne <= 64) {
    for (unsigned j = lane; j < ne; j += 64) {
      const unsigned short ix = eqbuf[wv][j];
      ibuf[wv][ngt + j] = ix;
      sbuf[wv][ngt + j] = __uint_as_float(row2[ix].y);
    }
  } else if (lane == 0) {
    if (ne <= 64) {                       // rare: sort ties ascending, keep lowest `need`
      for (unsigned a = 1; a < ne; ++a) {
        unsigned short kv = eqbuf[wv][a]; int bp = (int)a;
        while (bp > 0 && eqbuf[wv][bp - 1] > kv) { eqbuf[wv][bp] = eqbuf[wv][bp - 1]; --bp; }
        eqbuf[wv][bp] = kv;
      }
      for (unsigned j = 0; j < need; ++j) {
        const unsigned short ix = eqbuf[wv][j];
        ibuf[wv][ngt + j] = ix;
        sbuf[wv][ngt + j] = __uint_as_float(row2[ix].y);
      }
    } else {                              // pathological: serial ascending scan
      unsigned taken = 0;
      for (int i = 0; i < S_LEN && taken < need; ++i)
        if (row2[i].x == T) { ibuf[wv][ngt + taken] = (unsigned short)i; sbuf[wv][ngt + taken] = __uint_as_float(row2[i].y); ++taken; }
    }
  }
  WAVE_SYNC();

  // ---- softmax over the 256 selected scores ----
  float sc[4];
#pragma unroll
  for (int m = 0; m < 4; ++m) sc[m] = sbuf[wv][lane * 4 + m];
  float mx = fmaxf(fmaxf(sc[0], sc[1]), fmaxf(sc[2], sc[3]));
#pragma unroll
  for (int off = 32; off; off >>= 1) mx = fmaxf(mx, __shfl_xor(mx, off));
  float zs = 0.f;
#pragma unroll
  for (int m = 0; m < 4; ++m) { sc[m] = expf(sc[m] - mx); zs += sc[m]; }
#pragma unroll
  for (int off = 32; off; off >>= 1) zs += __shfl_xor(zs, off);
  const float rz = 1.0f / zs;
  *(float4*)&sbuf[wv][lane * 4] = make_float4(sc[0], sc[1], sc[2], sc[3]);
  WAVE_SYNC();

  // ---- PV: wave-contiguous 256B V-row reads, LDS broadcasts ----
  const int h = (int)(gr >> 11), q = (int)(gr & (S_LEN - 1));
  const float* Vh = V + h * DHEAD;
  float outv = 0.f;
#pragma unroll 4
  for (int j = 0; j < NSEL; j += 4) {
    const ushort4 id4 = *(const ushort4*)&ibuf[wv][j];
    const float4  w4  = *(const float4*)&sbuf[wv][j];
    outv += w4.x * Vh[(size_t)id4.x * HIDDEN + lane];
    outv += w4.y * Vh[(size_t)id4.y * HIDDEN + lane];
    outv += w4.z * Vh[(size_t)id4.z * HIDDEN + lane];
    outv += w4.w * Vh[(size_t)id4.w * HIDDEN + lane];
  }
  AO[(size_t)q * HIDDEN + h * DHEAD + lane] = outv * rz;
}

// ===================== validated fallbacks (round-3 / round-2) =====================
__global__ __launch_bounds__(256) void imp_gemm(const float* __restrict__ Q,
                                                const float* __restrict__ K,
                                                unsigned* __restrict__ impu) {
  __shared__ float Qs[32][68];
  __shared__ float Ks[32][68];
  const int bid  = blockIdx.x;
  const int h    = bid & (NHEAD - 1);
  const int tile = bid >> 3;
  const int q0   = (tile & 31) * 64;
  const int k0   = (tile >> 5) * 64;
  const int t  = threadIdx.x;
  const int tx = t & 15, ty = t >> 4;
#pragma unroll
  for (int s = 0; s < 2; ++s) {
    int slot = t + s * 256;
    int r = slot >> 3, c = (slot & 7) << 2;
    const float4 fq = *(const float4*)&Q[(size_t)(q0 + r) * HIDDEN + h * DHEAD + c];
    Qs[c + 0][r] = fq.x; Qs[c + 1][r] = fq.y; Qs[c + 2][r] = fq.z; Qs[c + 3][r] = fq.w;
    const float4 fk = *(const float4*)&K[(size_t)(k0 + r) * HIDDEN + h * DHEAD + c];
    Ks[c + 0][r] = fk.x; Ks[c + 1][r] = fk.y; Ks[c + 2][r] = fk.z; Ks[c + 3][r] = fk.w;
  }
  __syncthreads();
  float acc[4][4] = {};
#pragma unroll
  for (int d = 0; d < 32; ++d) {
    const float4 a4 = *(const float4*)&Qs[d][ty * 4];
    const float4 b4 = *(const float4*)&Ks[d][tx * 4];
    const float a[4] = {a4.x, a4.y, a4.z, a4.w};
    const float b[4] = {b4.x, b4.y, b4.z, b4.w};
#pragma unroll
    for (int i = 0; i < 4; ++i)
#pragma unroll
      for (int j = 0; j < 4; ++j) acc[i][j] += a[i] * b[j];
  }
#pragma unroll
  for (int i = 0; i < 4; ++i) {
    uint4 o = make_uint4(mapu(acc[i][0]), mapu(acc[i][1]), mapu(acc[i][2]), mapu(acc[i][3]));
    *(uint4*)&impu[((size_t)(h * S_LEN) + q0 + ty * 4 + i) * S_LEN + k0 + tx * 4] = o;
  }
}

__global__ __launch_bounds__(512) void radix_select(const unsigned* __restrict__ impu,
                                                    unsigned short* __restrict__ selg) {
  __shared__ unsigned hist[ROWS_A][256];
  __shared__ unsigned short selbuf[ROWS_A][NSEL];
  __shared__ unsigned short eqbuf[ROWS_A][64];
  __shared__ unsigned cnt[ROWS_A], eqcnt[ROWS_A];
  __shared__ unsigned rstate[ROWS_A][2];

  const int t = threadIdx.x, wv = t >> 6, lane = t & 63;
  const size_t gr = (size_t)blockIdx.x * ROWS_A + wv;
  const unsigned* rowp = impu + gr * S_LEN;

  uint4 u[8];
#pragma unroll
  for (int j = 0; j < 8; ++j) u[j] = *(const uint4*)&rowp[j * 256 + lane * 4];

  unsigned prefix = 0, krem = NSEL;
#pragma unroll 1
  for (int b = 3; b >= 0; --b) {
    hist[wv][lane] = 0; hist[wv][lane + 64] = 0; hist[wv][lane + 128] = 0; hist[wv][lane + 192] = 0;
    WAVE_SYNC();
    const int shift = b * 8;
#pragma unroll
    for (int j = 0; j < 8; ++j) {
      const unsigned uu[4] = {u[j].x, u[j].y, u[j].z, u[j].w};
#pragma unroll
      for (int e = 0; e < 4; ++e) {
        const unsigned v = uu[e];
        const bool ok = (b == 3) || ((v >> (shift + 8)) == prefix);
        if (ok) atomicAdd(&hist[wv][(v >> shift) & 0xFF], 1u);
      }
    }
    WAVE_SYNC();
    const int g = 63 - lane;
    const uint4 c4 = *(const uint4*)&hist[wv][4 * g];
    const unsigned c0 = c4.x, c1 = c4.y, c2 = c4.z, c3 = c4.w;
    const unsigned lsum = c0 + c1 + c2 + c3;
    unsigned incl = lsum;
#pragma unroll
    for (int off = 1; off < 64; off <<= 1) {
      unsigned o = __shfl_up(incl, off);
      if (lane >= off) incl += o;
    }
    const unsigned excl = incl - lsum;
    const unsigned ab3 = excl, ab2 = excl + c3, ab1 = excl + c3 + c2, ab0 = excl + c3 + c2 + c1;
    if (ab3 < krem && krem <= ab3 + c3) { rstate[wv][0] = 4u*g+3u; rstate[wv][1] = krem - ab3; }
    if (ab2 < krem && krem <= ab2 + c2) { rstate[wv][0] = 4u*g+2u; rstate[wv][1] = krem - ab2; }
    if (ab1 < krem && krem <= ab1 + c1) { rstate[wv][0] = 4u*g+1u; rstate[wv][1] = krem - ab1; }
    if (ab0 < krem && krem <= ab0 + c0) { rstate[wv][0] = 4u*g+0u; rstate[wv][1] = krem - ab0; }
    WAVE_SYNC();
    prefix = (prefix << 8) | rstate[wv][0];
    krem   = rstate[wv][1];
  }
  const unsigned T = prefix;

  if (lane == 0) { cnt[wv] = 0; eqcnt[wv] = 0; }
  WAVE_SYNC();
#pragma unroll
  for (int j = 0; j < 8; ++j) {
    const unsigned uu[4] = {u[j].x, u[j].y, u[j].z, u[j].w};
#pragma unroll
    for (int e = 0; e < 4; ++e) {
      const unsigned v = uu[e];
      const int i = j * 256 + lane * 4 + e;
      if (v > T)       { unsigned p = atomicAdd(&cnt[wv], 1u);   selbuf[wv][p] = (unsigned short)i; }
      else if (v == T) { unsigned p = atomicAdd(&eqcnt[wv], 1u); if (p < 64) eqbuf[wv][p] = (unsigned short)i; }
    }
  }
  WAVE_SYNC();
  const unsigned ngt = cnt[wv], ne = eqcnt[wv];
  const unsigned need = NSEL - ngt;
  if (ne == need && ne <= 64) {
    for (unsigned j = lane; j < ne; j += 64) selbuf[wv][ngt + j] = eqbuf[wv][j];
  } else if (lane == 0) {
    if (ne <= 64) {
      for (unsigned a = 1; a < ne; ++a) {
        unsigned short kv = eqbuf[wv][a]; int bp = (int)a;
        while (bp > 0 && eqbuf[wv][bp - 1] > kv) { eqbuf[wv][bp] = eqbuf[wv][bp - 1]; --bp; }
        eqbuf[wv][bp] = kv;
      }
      for (unsigned j = 0; j < need; ++j) selbuf[wv][ngt + j] = eqbuf[wv][j];
    } else {
      unsigned taken = 0;
      for (int i = 0; i < S_LEN && taken < need; ++i)
        if (rowp[i] == T) { selbuf[wv][ngt + taken] = (unsigned short)i; ++taken; }
    }
  }
  WAVE_SYNC();
  if (lane < 32) {
    const uint4 o = *(const uint4*)&selbuf[wv][lane * 8];
    *(uint4*)&selg[gr * NSEL + lane * 8] = o;
  }
}

__global__ __launch_bounds__(512, 4) void fasa_select(const float* __restrict__ Q,
                                                      const float* __restrict__ K,
                                                      unsigned short* __restrict__ selg) {
  __shared__ float    qs[ROWS_A][32];
  __shared__ unsigned impu[ROWS_A][S_LEN];
  __shared__ unsigned hist[ROWS_A][256];
  __shared__ unsigned short eqbuf[ROWS_A][64];
  __shared__ unsigned cnt[ROWS_A], eqcnt[ROWS_A];
  __shared__ unsigned rstate[ROWS_A][2];

  const int bid  = blockIdx.x;
  const int h    = bid & (NHEAD - 1);
  const int qb   = bid >> 3;
  const int row0 = qb * ROWS_A;
  const int t    = threadIdx.x;
  const int wv   = t >> 6, lane = t & 63;

  if (t < ROWS_A * 32) {
    int r = t >> 5, d = t & 31;
    qs[r][d] = Q[(size_t)(row0 + r) * HIDDEN + h * DHEAD + d];
  }
  __syncthreads();

  const float* Kh = K + h * DHEAD;
  {
    float acc[ROWS_A][4] = {};
#pragma unroll
    for (int k4 = 0; k4 < 8; ++k4) {
      float4 kf[4];
#pragma unroll
      for (int m = 0; m < 4; ++m)
        kf[m] = *(const float4*)&Kh[(size_t)(m * 512 + t) * HIDDEN + k4 * 4];
#pragma unroll
      for (int r = 0; r < ROWS_A; ++r) {
        const float4 qv = *(const float4*)&qs[r][k4 * 4];
#pragma unroll
        for (int m = 0; m < 4; ++m)
          acc[r][m] += kf[m].x * qv.x + kf[m].y * qv.y + kf[m].z * qv.z + kf[m].w * qv.w;
      }
    }
#pragma unroll
    for (int r = 0; r < ROWS_A; ++r)
#pragma unroll
      for (int m = 0; m < 4; ++m)
        impu[r][m * 512 + t] = mapu(acc[r][m]);
  }
  __syncthreads();

  unsigned prefix = 0, krem = NSEL;
#pragma unroll 1
  for (int b = 3; b >= 0; --b) {
    hist[wv][lane] = 0; hist[wv][lane + 64] = 0; hist[wv][lane + 128] = 0; hist[wv][lane + 192] = 0;
    WAVE_SYNC();
    const int shift = b * 8;
#pragma unroll 1
    for (int j = 0; j < 8; ++j) {
      const uint4 u4 = *(const uint4*)&impu[wv][j * 256 + lane * 4];
      const unsigned uu[4] = {u4.x, u4.y, u4.z, u4.w};
#pragma unroll
      for (int e = 0; e < 4; ++e) {
        const unsigned u = uu[e];
        const bool ok = (b == 3) || ((u >> (shift + 8)) == prefix);
        if (ok) atomicAdd(&hist[wv][(u >> shift) & 0xFF], 1u);
      }
    }
    WAVE_SYNC();
    const int g = 63 - lane;
    const uint4 c4 = *(const uint4*)&hist[wv][4 * g];
    const unsigned c0 = c4.x, c1 = c4.y, c2 = c4.z, c3 = c4.w;
    const unsigned lsum = c0 + c1 + c2 + c3;
    unsigned incl = lsum;
#pragma unroll
    for (int off = 1; off < 64; off <<= 1) {
      unsigned o = __shfl_up(incl, off);
      if (lane >= off) incl += o;
    }
    const unsigned excl = incl - lsum;
    const unsigned ab3 = excl, ab2 = excl + c3, ab1 = excl + c3 + c2, ab0 = excl + c3 + c2 + c1;
    if (ab3 < krem && krem <= ab3 + c3) { rstate[wv][0] = 4u*g+3u; rstate[wv][1] = krem - ab3; }
    if (ab2 < krem && krem <= ab2 + c2) { rstate[wv][0] = 4u*g+2u; rstate[wv][1] = krem - ab2; }
    if (ab1 < krem && krem <= ab1 + c1) { rstate[wv][0] = 4u*g+1u; rstate[wv][1] = krem - ab1; }
    if (ab0 < krem && krem <= ab0 + c0) { rstate[wv][0] = 4u*g+0u; rstate[wv][1] = krem - ab0; }
    WAVE_SYNC();
    prefix = (prefix << 8) | rstate[wv][0];
    krem   = rstate[wv][1];
  }
  const unsigned T = prefix;

  if (lane == 0) { cnt[wv] = 0; eqcnt[wv] = 0; }
  WAVE_SYNC();
  unsigned short* srow = selg + ((size_t)(h * S_LEN) + row0 + wv) * NSEL;
#pragma unroll 1
  for (int j = 0; j < 8; ++j) {
    const uint4 u4 = *(const uint4*)&impu[wv][j * 256 + lane * 4];
    const unsigned uu[4] = {u4.x, u4.y, u4.z, u4.w};
#pragma unroll
    for (int e = 0; e < 4; ++e) {
      const unsigned u = uu[e];
      const int i = j * 256 + lane * 4 + e;
      if (u > T)       { unsigned p = atomicAdd(&cnt[wv], 1u);   srow[p] = (unsigned short)i; }
      else if (u == T) { unsigned p = atomicAdd(&eqcnt[wv], 1u); if (p < 64) eqbuf[wv][p] = (unsigned short)i; }
    }
  }
  WAVE_SYNC();
  const unsigned ngt = cnt[wv], ne = eqcnt[wv];
  const unsigned need = NSEL - ngt;
  if (ne == need && ne <= 64) {
    for (unsigned j = lane; j < ne; j += 64) srow[ngt + j] = eqbuf[wv][j];
  } else if (lane == 0) {
    if (ne <= 64) {
      for (unsigned a = 1; a < ne; ++a) {
        unsigned short kv = eqbuf[wv][a]; int bp = (int)a;
        while (bp > 0 && eqbuf[wv][bp - 1] > kv) { eqbuf[wv][bp] = eqbuf[wv][bp - 1]; --bp; }
        eqbuf[wv][bp] = kv;
      }
      for (unsigned j = 0; j < need; ++j) srow[ngt + j] = eqbuf[wv][j];
    } else {
      unsigned taken = 0;
      for (int i = 0; i < S_LEN && taken < need; ++i)
        if (impu[wv][i] == T) { srow[ngt + taken] = (unsigned short)i; ++taken; }
    }
  }
}

__global__ __launch_bounds__(256, 4) void fasa_attend(const float* __restrict__ Q,
                                                      const float* __restrict__ K,
                                                      const float* __restrict__ V,
                                                      const unsigned short* __restrict__ selg,
                                                      float* __restrict__ O) {
  __shared__ float qs[4][DHEAD];
  __shared__ float wbuf[4][NSEL];
  __shared__ int   ibuf[4][NSEL];
  const int bid = blockIdx.x;
  const int h   = bid & (NHEAD - 1);
  const int qb  = bid >> 3;
  const int t   = threadIdx.x, wv = t >> 6, lane = t & 63;
  const int row = qb * 4 + wv;

  qs[wv][lane] = Q[(size_t)row * HIDDEN + h * DHEAD + lane];
  const unsigned short* srow = selg + ((size_t)(h * S_LEN) + row) * NSEL;
  const ushort4 s4 = *(const ushort4*)&srow[lane * 4];
  int sidx[4] = {(int)s4.x, (int)s4.y, (int)s4.z, (int)s4.w};
  WAVE_SYNC();

  const float* Kh = K + h * DHEAD;
  float sc[4] = {0.f, 0.f, 0.f, 0.f};
#pragma unroll
  for (int k4 = 0; k4 < 16; ++k4) {
    const float4 qv = *(const float4*)&qs[wv][k4 * 4];
#pragma unroll
    for (int m = 0; m < 4; ++m) {
      const float4 kf = *(const float4*)&Kh[(size_t)sidx[m] * HIDDEN + k4 * 4];
      sc[m] += kf.x * qv.x + kf.y * qv.y + kf.z * qv.z + kf.w * qv.w;
    }
  }
#pragma unroll
  for (int m = 0; m < 4; ++m) sc[m] *= SCALE_;

  float mx = fmaxf(fmaxf(sc[0], sc[1]), fmaxf(sc[2], sc[3]));
#pragma unroll
  for (int off = 32; off; off >>= 1) mx = fmaxf(mx, __shfl_xor(mx, off));
  float zs = 0.f;
#pragma unroll
  for (int m = 0; m < 4; ++m) { sc[m] = expf(sc[m] - mx); zs += sc[m]; }
#pragma unroll
  for (int off = 32; off; off >>= 1) zs += __shfl_xor(zs, off);
  const float rz = 1.0f / zs;

  *(float4*)&wbuf[wv][lane * 4] = make_float4(sc[0], sc[1], sc[2], sc[3]);
  *(int4*)&ibuf[wv][lane * 4]   = make_int4(sidx[0], sidx[1], sidx[2], sidx[3]);
  WAVE_SYNC();

  const float* Vh = V + h * DHEAD;
  float outv = 0.f;
#pragma unroll 4
  for (int j = 0; j < NSEL; j += 4) {
    const int4   id4 = *(const int4*)&ibuf[wv][j];
    const float4 w4  = *(const float4*)&wbuf[wv][j];
    outv += w4.x * Vh[(size_t)id4.x * HIDDEN + lane];
    outv += w4.y * Vh[(size_t)id4.y * HIDDEN + lane];
    outv += w4.z * Vh[(size_t)id4.z * HIDDEN + lane];
    outv += w4.w * Vh[(size_t)id4.w * HIDDEN + lane];
  }
  O[(size_t)row * HIDDEN + h * DHEAD + lane] = outv * rz;
}

extern "C" void kernel_launch(void* const* d_in, const int* in_sizes, int n_in,
                              void* d_out, int out_size, void* d_ws, size_t ws_size,
                              hipStream_t stream) {
  const float* x  = (const float*)d_in[0];
  const float* wq = (const float*)d_in[1];
  const float* wk = (const float*)d_in[2];
  const float* wv = (const float*)d_in[3];
  const float* wo = (const float*)d_in[4];
  float* out = (float*)d_out;

  float* Qb = (float*)d_ws;
  float* Kb = Qb + (size_t)S_LEN * HIDDEN;
  float* Vb = Kb + (size_t)S_LEN * HIDDEN;
  float* AO = Vb + (size_t)S_LEN * HIDDEN;
  void*  tail = (void*)(AO + (size_t)S_LEN * HIDDEN);

  const size_t base = (size_t)4 * S_LEN * HIDDEN * 4;                    // Q,K,V,AO = 16 MB
  const size_t need_new = base + (size_t)NHEAD * S_LEN * S_LEN * 8;      // + sd (uint2) 256 MB
  const size_t need_r3  = base + (size_t)NHEAD * S_LEN * NSEL * 2
                               + (size_t)NHEAD * S_LEN * S_LEN * 4;      // + selg + impu

  dim3 g(S_LEN / 64, HIDDEN / 64);
  gemm_nt<<<g, 256, 0, stream>>>(x, wq, Qb, S_LEN, HIDDEN, HIDDEN);
  gemm_nt<<<g, 256, 0, stream>>>(x, wk, Kb, S_LEN, HIDDEN, HIDDEN);
  gemm_nt<<<g, 256, 0, stream>>>(x, wv, Vb, S_LEN, HIDDEN, HIDDEN);
  if (ws_size >= need_new) {
    uint2* sd = (uint2*)tail;
    score_gemm<<<dim3(NHEAD * 16 * 32), 256, 0, stream>>>(Qb, Kb, sd);
    fused_select_pv<<<dim3(NHEAD * S_LEN / ROWS_A), 512, 0, stream>>>(sd, Vb, AO);
  } else if (ws_size >= need_r3) {
    unsigned short* selg = (unsigned short*)tail;
    unsigned* impu = (unsigned*)(selg + (size_t)NHEAD * S_LEN * NSEL);
    imp_gemm<<<dim3(NHEAD * 32 * 32), 256, 0, stream>>>(Qb, Kb, impu);
    radix_select<<<dim3(NHEAD * S_LEN / ROWS_A), 512, 0, stream>>>(impu, selg);
    fasa_attend<<<dim3((S_LEN / 4) * NHEAD), 256, 0, stream>>>(Qb, Kb, Vb, selg, AO);
  } else {
    unsigned short* selg = (unsigned short*)tail;
    fasa_select<<<dim3((S_LEN / ROWS_A) * NHEAD), 512, 0, stream>>>(Qb, Kb, selg);
    fasa_attend<<<dim3((S_LEN / 4) * NHEAD), 256, 0, stream>>>(Qb, Kb, Vb, selg, AO);
  }
  gemm_nt<<<g, 256, 0, stream>>>(AO, wo, out, S_LEN, HIDDEN, HIDDEN);
}

// Round 5
// 284.521 us; speedup vs baseline: 1.7507x; 1.7507x over previous
//
#include <hip/hip_runtime.h>

#define S_LEN  2048
#define HIDDEN 512
#define NHEAD  8
#define DHEAD  64
#define NSEL   256
#define ROWS_A 8
#define SCALE_ 0.125f

// intra-wave LDS producer->consumer sync (lockstep lanes + drain LDS queue)
#define WAVE_SYNC() __asm__ volatile("s_waitcnt lgkmcnt(0)" ::: "memory")

// monotone float->uint mapping (ascending float == ascending uint)
__device__ __forceinline__ unsigned mapu(float f) {
  unsigned u = __float_as_uint(f);
  return (u & 0x80000000u) ? ~u : (u | 0x80000000u);
}

union H4 { _Float16 h[4]; uint2 u2; };   // 4 packed fp16 <-> 8B

// C[m][n] = sum_k A[m][k] * B[n][k]   (A: MxK, B: NxK, row-major)
__global__ __launch_bounds__(256) void gemm_nt(const float* __restrict__ A,
                                               const float* __restrict__ B,
                                               float* __restrict__ C,
                                               int M, int N, int K) {
  __shared__ float As[32][68];   // [k][m]
  __shared__ float Bs[32][68];   // [k][n]
  const int m0 = blockIdx.x * 64, n0 = blockIdx.y * 64;
  const int t  = threadIdx.x;
  const int tx = t & 15, ty = t >> 4;
  float acc[4][4] = {};
  for (int k0 = 0; k0 < K; k0 += 32) {
    __syncthreads();
#pragma unroll
    for (int s = 0; s < 2; ++s) {
      int slot = t + s * 256;
      int r = slot >> 3, c = (slot & 7) << 2;
      const float4 fa = *(const float4*)&A[(size_t)(m0 + r) * K + k0 + c];
      As[c + 0][r] = fa.x; As[c + 1][r] = fa.y; As[c + 2][r] = fa.z; As[c + 3][r] = fa.w;
      const float4 fb = *(const float4*)&B[(size_t)(n0 + r) * K + k0 + c];
      Bs[c + 0][r] = fb.x; Bs[c + 1][r] = fb.y; Bs[c + 2][r] = fb.z; Bs[c + 3][r] = fb.w;
    }
    __syncthreads();
#pragma unroll
    for (int kk = 0; kk < 32; ++kk) {
      const float4 a4 = *(const float4*)&As[kk][ty * 4];
      const float4 b4 = *(const float4*)&Bs[kk][tx * 4];
      const float a[4] = {a4.x, a4.y, a4.z, a4.w};
      const float b[4] = {b4.x, b4.y, b4.z, b4.w};
#pragma unroll
      for (int i = 0; i < 4; ++i)
#pragma unroll
        for (int j = 0; j < 4; ++j) acc[i][j] += a[i] * b[j];
    }
  }
#pragma unroll
  for (int i = 0; i < 4; ++i) {
    float4 o = make_float4(acc[i][0], acc[i][1], acc[i][2], acc[i][3]);
    *(float4*)&C[(size_t)(m0 + ty * 4 + i) * N + n0 + tx * 4] = o;
  }
}

// Fused importance+score GEMM. Tile 128q x 64k, depth 64.
// impu[h*S+q][k] = mapu(dot_{d<32})   (u32 exact, selection bits)
// sch [h*S+q][k] = fp16(dot_{d<64} * SCALE)
// importance contraction chain identical to validated imp_gemm.
__global__ __launch_bounds__(256) void score_gemm(const float* __restrict__ Q,
                                                  const float* __restrict__ K,
                                                  unsigned* __restrict__ impu,
                                                  _Float16* __restrict__ sch) {
  __shared__ float Qs[64][132];   // [d][q], 33.8 KB
  __shared__ float Ks[64][68];    // [d][k], 17.4 KB
  const int bid  = blockIdx.x;
  const int h    = bid & (NHEAD - 1);
  const int tile = bid >> 3;
  const int q0   = (tile & 15) * 128;   // 16 q-tiles
  const int k0   = (tile >> 4) * 64;    // 32 k-tiles
  const int t  = threadIdx.x;
  const int tx = t & 15, ty = t >> 4;   // tx: 4 k-cols, ty: 8 q-rows

#pragma unroll
  for (int s = 0; s < 8; ++s) {
    const int sf = s * 256 + t;
    const int r = sf >> 4, c = (sf & 15) * 4;
    const float4 f = *(const float4*)&Q[(size_t)(q0 + r) * HIDDEN + h * DHEAD + c];
    Qs[c + 0][r] = f.x; Qs[c + 1][r] = f.y; Qs[c + 2][r] = f.z; Qs[c + 3][r] = f.w;
  }
#pragma unroll
  for (int s = 0; s < 4; ++s) {
    const int sf = s * 256 + t;
    const int r = sf >> 4, c = (sf & 15) * 4;
    const float4 f = *(const float4*)&K[(size_t)(k0 + r) * HIDDEN + h * DHEAD + c];
    Ks[c + 0][r] = f.x; Ks[c + 1][r] = f.y; Ks[c + 2][r] = f.z; Ks[c + 3][r] = f.w;
  }
  __syncthreads();

  float acc[8][4] = {};
#pragma unroll
  for (int d = 0; d < 32; ++d) {
    const float4 aa = *(const float4*)&Qs[d][ty * 8];
    const float4 ab = *(const float4*)&Qs[d][ty * 8 + 4];
    const float4 b4 = *(const float4*)&Ks[d][tx * 4];
    const float a[8] = {aa.x, aa.y, aa.z, aa.w, ab.x, ab.y, ab.z, ab.w};
    const float b[4] = {b4.x, b4.y, b4.z, b4.w};
#pragma unroll
    for (int i = 0; i < 8; ++i)
#pragma unroll
      for (int j = 0; j < 4; ++j) acc[i][j] += a[i] * b[j];
  }
  float simp[8][4];
#pragma unroll
  for (int i = 0; i < 8; ++i)
#pragma unroll
    for (int j = 0; j < 4; ++j) simp[i][j] = acc[i][j];   // importance snapshot (d<32)
#pragma unroll
  for (int d = 32; d < 64; ++d) {
    const float4 aa = *(const float4*)&Qs[d][ty * 8];
    const float4 ab = *(const float4*)&Qs[d][ty * 8 + 4];
    const float4 b4 = *(const float4*)&Ks[d][tx * 4];
    const float a[8] = {aa.x, aa.y, aa.z, aa.w, ab.x, ab.y, ab.z, ab.w};
    const float b[4] = {b4.x, b4.y, b4.z, b4.w};
#pragma unroll
    for (int i = 0; i < 8; ++i)
#pragma unroll
      for (int j = 0; j < 4; ++j) acc[i][j] += a[i] * b[j];
  }

#pragma unroll
  for (int i = 0; i < 8; ++i) {
    const size_t gr = (size_t)(h * S_LEN) + q0 + ty * 8 + i;
    const size_t off = gr * S_LEN + k0 + tx * 4;
    *(uint4*)&impu[off] = make_uint4(mapu(simp[i][0]), mapu(simp[i][1]),
                                     mapu(simp[i][2]), mapu(simp[i][3]));
    H4 pk;
#pragma unroll
    for (int j = 0; j < 4; ++j) pk.h[j] = (_Float16)(acc[i][j] * SCALE_);
    *(uint2*)&sch[off] = pk.u2;
  }
}

// One wave per row. imp row -> 8 uint4/lane, score row -> 8 ushort4/lane
// (matching element indexing). Radix top-256 on imp, softmax on in-register
// fp16 scores, PV with wave-contiguous V reads. Zero scattered K reads.
__global__ __launch_bounds__(512) void fused_select_pv(const unsigned* __restrict__ impu,
                                                       const _Float16* __restrict__ sch,
                                                       const float* __restrict__ V,
                                                       float* __restrict__ AO) {
  __shared__ unsigned hist[ROWS_A][256];           // 8 KB
  __shared__ float    sbuf[ROWS_A][NSEL];          // 8 KB
  __shared__ unsigned short ibuf[ROWS_A][NSEL];    // 4 KB
  __shared__ unsigned short eqbuf[ROWS_A][64];     // 1 KB
  __shared__ unsigned cnt[ROWS_A], eqcnt[ROWS_A];
  __shared__ unsigned rstate[ROWS_A][2];

  const int t = threadIdx.x, wv = t >> 6, lane = t & 63;
  const size_t gr = (size_t)blockIdx.x * ROWS_A + wv;   // gr = h*S + q
  const unsigned* rowp  = impu + gr * S_LEN;
  const _Float16* shrow = sch  + gr * S_LEN;

  uint4 u[8];
  H4    s4[8];
#pragma unroll
  for (int j = 0; j < 8; ++j) {
    u[j]     = *(const uint4*)&rowp[j * 256 + lane * 4];
    s4[j].u2 = *(const uint2*)&shrow[j * 256 + lane * 4];
  }
  // element idx for u[j]/s4[j] component e: j*256 + lane*4 + e

  // ---- exact top-256 threshold: 4-round byte radix on imp (registers) ----
  unsigned prefix = 0, krem = NSEL;
#pragma unroll 1
  for (int b = 3; b >= 0; --b) {
    hist[wv][lane] = 0; hist[wv][lane + 64] = 0; hist[wv][lane + 128] = 0; hist[wv][lane + 192] = 0;
    WAVE_SYNC();
    const int shift = b * 8;
#pragma unroll
    for (int j = 0; j < 8; ++j) {
      const unsigned uu[4] = {u[j].x, u[j].y, u[j].z, u[j].w};
#pragma unroll
      for (int e = 0; e < 4; ++e) {
        const unsigned v = uu[e];
        const bool ok = (b == 3) || ((v >> (shift + 8)) == prefix);
        if (ok) atomicAdd(&hist[wv][(v >> shift) & 0xFF], 1u);
      }
    }
    WAVE_SYNC();
    const int g = 63 - lane;
    const uint4 c4 = *(const uint4*)&hist[wv][4 * g];
    const unsigned c0 = c4.x, c1 = c4.y, c2 = c4.z, c3 = c4.w;
    const unsigned lsum = c0 + c1 + c2 + c3;
    unsigned incl = lsum;
#pragma unroll
    for (int off = 1; off < 64; off <<= 1) {
      unsigned o = __shfl_up(incl, off);
      if (lane >= off) incl += o;
    }
    const unsigned excl = incl - lsum;
    const unsigned ab3 = excl, ab2 = excl + c3, ab1 = excl + c3 + c2, ab0 = excl + c3 + c2 + c1;
    if (ab3 < krem && krem <= ab3 + c3) { rstate[wv][0] = 4u*g+3u; rstate[wv][1] = krem - ab3; }
    if (ab2 < krem && krem <= ab2 + c2) { rstate[wv][0] = 4u*g+2u; rstate[wv][1] = krem - ab2; }
    if (ab1 < krem && krem <= ab1 + c1) { rstate[wv][0] = 4u*g+1u; rstate[wv][1] = krem - ab1; }
    if (ab0 < krem && krem <= ab0 + c0) { rstate[wv][0] = 4u*g+0u; rstate[wv][1] = krem - ab0; }
    WAVE_SYNC();
    prefix = (prefix << 8) | rstate[wv][0];
    krem   = rstate[wv][1];
  }
  const unsigned T = prefix;

  // ---- collect selected (idx, score) into LDS ----
  if (lane == 0) { cnt[wv] = 0; eqcnt[wv] = 0; }
  WAVE_SYNC();
#pragma unroll
  for (int j = 0; j < 8; ++j) {
    const unsigned uu[4] = {u[j].x, u[j].y, u[j].z, u[j].w};
#pragma unroll
    for (int e = 0; e < 4; ++e) {
      const unsigned v = uu[e];
      const int i = j * 256 + lane * 4 + e;
      if (v > T) {
        unsigned p = atomicAdd(&cnt[wv], 1u);
        ibuf[wv][p] = (unsigned short)i;
        sbuf[wv][p] = (float)s4[j].h[e];
      } else if (v == T) {
        unsigned p = atomicAdd(&eqcnt[wv], 1u);
        if (p < 64) eqbuf[wv][p] = (unsigned short)i;
      }
    }
  }
  WAVE_SYNC();
  const unsigned ngt = cnt[wv], ne = eqcnt[wv];
  const unsigned need = NSEL - ngt;
  if (ne == need && ne <= 64) {
    for (unsigned j = lane; j < ne; j += 64) {
      const unsigned short ix = eqbuf[wv][j];
      ibuf[wv][ngt + j] = ix;
      sbuf[wv][ngt + j] = (float)shrow[ix];
    }
  } else if (lane == 0) {
    if (ne <= 64) {                       // rare: sort ties ascending, keep lowest `need`
      for (unsigned a = 1; a < ne; ++a) {
        unsigned short kv = eqbuf[wv][a]; int bp = (int)a;
        while (bp > 0 && eqbuf[wv][bp - 1] > kv) { eqbuf[wv][bp] = eqbuf[wv][bp - 1]; --bp; }
        eqbuf[wv][bp] = kv;
      }
      for (unsigned j = 0; j < need; ++j) {
        const unsigned short ix = eqbuf[wv][j];
        ibuf[wv][ngt + j] = ix;
        sbuf[wv][ngt + j] = (float)shrow[ix];
      }
    } else {                              // pathological: serial ascending scan
      unsigned taken = 0;
      for (int i = 0; i < S_LEN && taken < need; ++i)
        if (rowp[i] == T) { ibuf[wv][ngt + taken] = (unsigned short)i; sbuf[wv][ngt + taken] = (float)shrow[i]; ++taken; }
    }
  }
  WAVE_SYNC();

  // ---- softmax over the 256 selected scores ----
  float sc[4];
#pragma unroll
  for (int m = 0; m < 4; ++m) sc[m] = sbuf[wv][lane * 4 + m];
  float mx = fmaxf(fmaxf(sc[0], sc[1]), fmaxf(sc[2], sc[3]));
#pragma unroll
  for (int off = 32; off; off >>= 1) mx = fmaxf(mx, __shfl_xor(mx, off));
  float zs = 0.f;
#pragma unroll
  for (int m = 0; m < 4; ++m) { sc[m] = expf(sc[m] - mx); zs += sc[m]; }
#pragma unroll
  for (int off = 32; off; off >>= 1) zs += __shfl_xor(zs, off);
  const float rz = 1.0f / zs;
  *(float4*)&sbuf[wv][lane * 4] = make_float4(sc[0], sc[1], sc[2], sc[3]);
  WAVE_SYNC();

  // ---- PV: wave-contiguous 256B V-row reads, LDS broadcasts ----
  const int h = (int)(gr >> 11), q = (int)(gr & (S_LEN - 1));
  const float* Vh = V + h * DHEAD;
  float outv = 0.f;
#pragma unroll 4
  for (int j = 0; j < NSEL; j += 4) {
    const ushort4 id4 = *(const ushort4*)&ibuf[wv][j];
    const float4  w4  = *(const float4*)&sbuf[wv][j];
    outv += w4.x * Vh[(size_t)id4.x * HIDDEN + lane];
    outv += w4.y * Vh[(size_t)id4.y * HIDDEN + lane];
    outv += w4.z * Vh[(size_t)id4.z * HIDDEN + lane];
    outv += w4.w * Vh[(size_t)id4.w * HIDDEN + lane];
  }
  AO[(size_t)q * HIDDEN + h * DHEAD + lane] = outv * rz;
}

// ===================== validated fallbacks (round-3 / round-2) =====================
__global__ __launch_bounds__(256) void imp_gemm(const float* __restrict__ Q,
                                                const float* __restrict__ K,
                                                unsigned* __restrict__ impu) {
  __shared__ float Qs[32][68];
  __shared__ float Ks[32][68];
  const int bid  = blockIdx.x;
  const int h    = bid & (NHEAD - 1);
  const int tile = bid >> 3;
  const int q0   = (tile & 31) * 64;
  const int k0   = (tile >> 5) * 64;
  const int t  = threadIdx.x;
  const int tx = t & 15, ty = t >> 4;
#pragma unroll
  for (int s = 0; s < 2; ++s) {
    int slot = t + s * 256;
    int r = slot >> 3, c = (slot & 7) << 2;
    const float4 fq = *(const float4*)&Q[(size_t)(q0 + r) * HIDDEN + h * DHEAD + c];
    Qs[c + 0][r] = fq.x; Qs[c + 1][r] = fq.y; Qs[c + 2][r] = fq.z; Qs[c + 3][r] = fq.w;
    const float4 fk = *(const float4*)&K[(size_t)(k0 + r) * HIDDEN + h * DHEAD + c];
    Ks[c + 0][r] = fk.x; Ks[c + 1][r] = fk.y; Ks[c + 2][r] = fk.z; Ks[c + 3][r] = fk.w;
  }
  __syncthreads();
  float acc[4][4] = {};
#pragma unroll
  for (int d = 0; d < 32; ++d) {
    const float4 a4 = *(const float4*)&Qs[d][ty * 4];
    const float4 b4 = *(const float4*)&Ks[d][tx * 4];
    const float a[4] = {a4.x, a4.y, a4.z, a4.w};
    const float b[4] = {b4.x, b4.y, b4.z, b4.w};
#pragma unroll
    for (int i = 0; i < 4; ++i)
#pragma unroll
      for (int j = 0; j < 4; ++j) acc[i][j] += a[i] * b[j];
  }
#pragma unroll
  for (int i = 0; i < 4; ++i) {
    uint4 o = make_uint4(mapu(acc[i][0]), mapu(acc[i][1]), mapu(acc[i][2]), mapu(acc[i][3]));
    *(uint4*)&impu[((size_t)(h * S_LEN) + q0 + ty * 4 + i) * S_LEN + k0 + tx * 4] = o;
  }
}

__global__ __launch_bounds__(512) void radix_select(const unsigned* __restrict__ impu,
                                                    unsigned short* __restrict__ selg) {
  __shared__ unsigned hist[ROWS_A][256];
  __shared__ unsigned short selbuf[ROWS_A][NSEL];
  __shared__ unsigned short eqbuf[ROWS_A][64];
  __shared__ unsigned cnt[ROWS_A], eqcnt[ROWS_A];
  __shared__ unsigned rstate[ROWS_A][2];

  const int t = threadIdx.x, wv = t >> 6, lane = t & 63;
  const size_t gr = (size_t)blockIdx.x * ROWS_A + wv;
  const unsigned* rowp = impu + gr * S_LEN;

  uint4 u[8];
#pragma unroll
  for (int j = 0; j < 8; ++j) u[j] = *(const uint4*)&rowp[j * 256 + lane * 4];

  unsigned prefix = 0, krem = NSEL;
#pragma unroll 1
  for (int b = 3; b >= 0; --b) {
    hist[wv][lane] = 0; hist[wv][lane + 64] = 0; hist[wv][lane + 128] = 0; hist[wv][lane + 192] = 0;
    WAVE_SYNC();
    const int shift = b * 8;
#pragma unroll
    for (int j = 0; j < 8; ++j) {
      const unsigned uu[4] = {u[j].x, u[j].y, u[j].z, u[j].w};
#pragma unroll
      for (int e = 0; e < 4; ++e) {
        const unsigned v = uu[e];
        const bool ok = (b == 3) || ((v >> (shift + 8)) == prefix);
        if (ok) atomicAdd(&hist[wv][(v >> shift) & 0xFF], 1u);
      }
    }
    WAVE_SYNC();
    const int g = 63 - lane;
    const uint4 c4 = *(const uint4*)&hist[wv][4 * g];
    const unsigned c0 = c4.x, c1 = c4.y, c2 = c4.z, c3 = c4.w;
    const unsigned lsum = c0 + c1 + c2 + c3;
    unsigned incl = lsum;
#pragma unroll
    for (int off = 1; off < 64; off <<= 1) {
      unsigned o = __shfl_up(incl, off);
      if (lane >= off) incl += o;
    }
    const unsigned excl = incl - lsum;
    const unsigned ab3 = excl, ab2 = excl + c3, ab1 = excl + c3 + c2, ab0 = excl + c3 + c2 + c1;
    if (ab3 < krem && krem <= ab3 + c3) { rstate[wv][0] = 4u*g+3u; rstate[wv][1] = krem - ab3; }
    if (ab2 < krem && krem <= ab2 + c2) { rstate[wv][0] = 4u*g+2u; rstate[wv][1] = krem - ab2; }
    if (ab1 < krem && krem <= ab1 + c1) { rstate[wv][0] = 4u*g+1u; rstate[wv][1] = krem - ab1; }
    if (ab0 < krem && krem <= ab0 + c0) { rstate[wv][0] = 4u*g+0u; rstate[wv][1] = krem - ab0; }
    WAVE_SYNC();
    prefix = (prefix << 8) | rstate[wv][0];
    krem   = rstate[wv][1];
  }
  const unsigned T = prefix;

  if (lane == 0) { cnt[wv] = 0; eqcnt[wv] = 0; }
  WAVE_SYNC();
#pragma unroll
  for (int j = 0; j < 8; ++j) {
    const unsigned uu[4] = {u[j].x, u[j].y, u[j].z, u[j].w};
#pragma unroll
    for (int e = 0; e < 4; ++e) {
      const unsigned v = uu[e];
      const int i = j * 256 + lane * 4 + e;
      if (v > T)       { unsigned p = atomicAdd(&cnt[wv], 1u);   selbuf[wv][p] = (unsigned short)i; }
      else if (v == T) { unsigned p = atomicAdd(&eqcnt[wv], 1u); if (p < 64) eqbuf[wv][p] = (unsigned short)i; }
    }
  }
  WAVE_SYNC();
  const unsigned ngt = cnt[wv], ne = eqcnt[wv];
  const unsigned need = NSEL - ngt;
  if (ne == need && ne <= 64) {
    for (unsigned j = lane; j < ne; j += 64) selbuf[wv][ngt + j] = eqbuf[wv][j];
  } else if (lane == 0) {
    if (ne <= 64) {
      for (unsigned a = 1; a < ne; ++a) {
        unsigned short kv = eqbuf[wv][a]; int bp = (int)a;
        while (bp > 0 && eqbuf[wv][bp - 1] > kv) { eqbuf[wv][bp] = eqbuf[wv][bp - 1]; --bp; }
        eqbuf[wv][bp] = kv;
      }
      for (unsigned j = 0; j < need; ++j) selbuf[wv][ngt + j] = eqbuf[wv][j];
    } else {
      unsigned taken = 0;
      for (int i = 0; i < S_LEN && taken < need; ++i)
        if (rowp[i] == T) { selbuf[wv][ngt + taken] = (unsigned short)i; ++taken; }
    }
  }
  WAVE_SYNC();
  if (lane < 32) {
    const uint4 o = *(const uint4*)&selbuf[wv][lane * 8];
    *(uint4*)&selg[gr * NSEL + lane * 8] = o;
  }
}

__global__ __launch_bounds__(512, 4) void fasa_select(const float* __restrict__ Q,
                                                      const float* __restrict__ K,
                                                      unsigned short* __restrict__ selg) {
  __shared__ float    qs[ROWS_A][32];
  __shared__ unsigned impu[ROWS_A][S_LEN];
  __shared__ unsigned hist[ROWS_A][256];
  __shared__ unsigned short eqbuf[ROWS_A][64];
  __shared__ unsigned cnt[ROWS_A], eqcnt[ROWS_A];
  __shared__ unsigned rstate[ROWS_A][2];

  const int bid  = blockIdx.x;
  const int h    = bid & (NHEAD - 1);
  const int qb   = bid >> 3;
  const int row0 = qb * ROWS_A;
  const int t    = threadIdx.x;
  const int wv   = t >> 6, lane = t & 63;

  if (t < ROWS_A * 32) {
    int r = t >> 5, d = t & 31;
    qs[r][d] = Q[(size_t)(row0 + r) * HIDDEN + h * DHEAD + d];
  }
  __syncthreads();

  const float* Kh = K + h * DHEAD;
  {
    float acc[ROWS_A][4] = {};
#pragma unroll
    for (int k4 = 0; k4 < 8; ++k4) {
      float4 kf[4];
#pragma unroll
      for (int m = 0; m < 4; ++m)
        kf[m] = *(const float4*)&Kh[(size_t)(m * 512 + t) * HIDDEN + k4 * 4];
#pragma unroll
      for (int r = 0; r < ROWS_A; ++r) {
        const float4 qv = *(const float4*)&qs[r][k4 * 4];
#pragma unroll
        for (int m = 0; m < 4; ++m)
          acc[r][m] += kf[m].x * qv.x + kf[m].y * qv.y + kf[m].z * qv.z + kf[m].w * qv.w;
      }
    }
#pragma unroll
    for (int r = 0; r < ROWS_A; ++r)
#pragma unroll
      for (int m = 0; m < 4; ++m)
        impu[r][m * 512 + t] = mapu(acc[r][m]);
  }
  __syncthreads();

  unsigned prefix = 0, krem = NSEL;
#pragma unroll 1
  for (int b = 3; b >= 0; --b) {
    hist[wv][lane] = 0; hist[wv][lane + 64] = 0; hist[wv][lane + 128] = 0; hist[wv][lane + 192] = 0;
    WAVE_SYNC();
    const int shift = b * 8;
#pragma unroll 1
    for (int j = 0; j < 8; ++j) {
      const uint4 u4 = *(const uint4*)&impu[wv][j * 256 + lane * 4];
      const unsigned uu[4] = {u4.x, u4.y, u4.z, u4.w};
#pragma unroll
      for (int e = 0; e < 4; ++e) {
        const unsigned u = uu[e];
        const bool ok = (b == 3) || ((u >> (shift + 8)) == prefix);
        if (ok) atomicAdd(&hist[wv][(u >> shift) & 0xFF], 1u);
      }
    }
    WAVE_SYNC();
    const int g = 63 - lane;
    const uint4 c4 = *(const uint4*)&hist[wv][4 * g];
    const unsigned c0 = c4.x, c1 = c4.y, c2 = c4.z, c3 = c4.w;
    const unsigned lsum = c0 + c1 + c2 + c3;
    unsigned incl = lsum;
#pragma unroll
    for (int off = 1; off < 64; off <<= 1) {
      unsigned o = __shfl_up(incl, off);
      if (lane >= off) incl += o;
    }
    const unsigned excl = incl - lsum;
    const unsigned ab3 = excl, ab2 = excl + c3, ab1 = excl + c3 + c2, ab0 = excl + c3 + c2 + c1;
    if (ab3 < krem && krem <= ab3 + c3) { rstate[wv][0] = 4u*g+3u; rstate[wv][1] = krem - ab3; }
    if (ab2 < krem && krem <= ab2 + c2) { rstate[wv][0] = 4u*g+2u; rstate[wv][1] = krem - ab2; }
    if (ab1 < krem && krem <= ab1 + c1) { rstate[wv][0] = 4u*g+1u; rstate[wv][1] = krem - ab1; }
    if (ab0 < krem && krem <= ab0 + c0) { rstate[wv][0] = 4u*g+0u; rstate[wv][1] = krem - ab0; }
    WAVE_SYNC();
    prefix = (prefix << 8) | rstate[wv][0];
    krem   = rstate[wv][1];
  }
  const unsigned T = prefix;

  if (lane == 0) { cnt[wv] = 0; eqcnt[wv] = 0; }
  WAVE_SYNC();
  unsigned short* srow = selg + ((size_t)(h * S_LEN) + row0 + wv) * NSEL;
#pragma unroll 1
  for (int j = 0; j < 8; ++j) {
    const uint4 u4 = *(const uint4*)&impu[wv][j * 256 + lane * 4];
    const unsigned uu[4] = {u4.x, u4.y, u4.z, u4.w};
#pragma unroll
    for (int e = 0; e < 4; ++e) {
      const unsigned u = uu[e];
      const int i = j * 256 + lane * 4 + e;
      if (u > T)       { unsigned p = atomicAdd(&cnt[wv], 1u);   srow[p] = (unsigned short)i; }
      else if (u == T) { unsigned p = atomicAdd(&eqcnt[wv], 1u); if (p < 64) eqbuf[wv][p] = (unsigned short)i; }
    }
  }
  WAVE_SYNC();
  const unsigned ngt = cnt[wv], ne = eqcnt[wv];
  const unsigned need = NSEL - ngt;
  if (ne == need && ne <= 64) {
    for (unsigned j = lane; j < ne; j += 64) srow[ngt + j] = eqbuf[wv][j];
  } else if (lane == 0) {
    if (ne <= 64) {
      for (unsigned a = 1; a < ne; ++a) {
        unsigned short kv = eqbuf[wv][a]; int bp = (int)a;
        while (bp > 0 && eqbuf[wv][bp - 1] > kv) { eqbuf[wv][bp] = eqbuf[wv][bp - 1]; --bp; }
        eqbuf[wv][bp] = kv;
      }
      for (unsigned j = 0; j < need; ++j) srow[ngt + j] = eqbuf[wv][j];
    } else {
      unsigned taken = 0;
      for (int i = 0; i < S_LEN && taken < need; ++i)
        if (impu[wv][i] == T) { srow[ngt + taken] = (unsigned short)i; ++taken; }
    }
  }
}

__global__ __launch_bounds__(256, 4) void fasa_attend(const float* __restrict__ Q,
                                                      const float* __restrict__ K,
                                                      const float* __restrict__ V,
                                                      const unsigned short* __restrict__ selg,
                                                      float* __restrict__ O) {
  __shared__ float qs[4][DHEAD];
  __shared__ float wbuf[4][NSEL];
  __shared__ int   ibuf[4][NSEL];
  const int bid = blockIdx.x;
  const int h   = bid & (NHEAD - 1);
  const int qb  = bid >> 3;
  const int t   = threadIdx.x, wv = t >> 6, lane = t & 63;
  const int row = qb * 4 + wv;

  qs[wv][lane] = Q[(size_t)row * HIDDEN + h * DHEAD + lane];
  const unsigned short* srow = selg + ((size_t)(h * S_LEN) + row) * NSEL;
  const ushort4 s4 = *(const ushort4*)&srow[lane * 4];
  int sidx[4] = {(int)s4.x, (int)s4.y, (int)s4.z, (int)s4.w};
  WAVE_SYNC();

  const float* Kh = K + h * DHEAD;
  float sc[4] = {0.f, 0.f, 0.f, 0.f};
#pragma unroll
  for (int k4 = 0; k4 < 16; ++k4) {
    const float4 qv = *(const float4*)&qs[wv][k4 * 4];
#pragma unroll
    for (int m = 0; m < 4; ++m) {
      const float4 kf = *(const float4*)&Kh[(size_t)sidx[m] * HIDDEN + k4 * 4];
      sc[m] += kf.x * qv.x + kf.y * qv.y + kf.z * qv.z + kf.w * qv.w;
    }
  }
#pragma unroll
  for (int m = 0; m < 4; ++m) sc[m] *= SCALE_;

  float mx = fmaxf(fmaxf(sc[0], sc[1]), fmaxf(sc[2], sc[3]));
#pragma unroll
  for (int off = 32; off; off >>= 1) mx = fmaxf(mx, __shfl_xor(mx, off));
  float zs = 0.f;
#pragma unroll
  for (int m = 0; m < 4; ++m) { sc[m] = expf(sc[m] - mx); zs += sc[m]; }
#pragma unroll
  for (int off = 32; off; off >>= 1) zs += __shfl_xor(zs, off);
  const float rz = 1.0f / zs;

  *(float4*)&wbuf[wv][lane * 4] = make_float4(sc[0], sc[1], sc[2], sc[3]);
  *(int4*)&ibuf[wv][lane * 4]   = make_int4(sidx[0], sidx[1], sidx[2], sidx[3]);
  WAVE_SYNC();

  const float* Vh = V + h * DHEAD;
  float outv = 0.f;
#pragma unroll 4
  for (int j = 0; j < NSEL; j += 4) {
    const int4   id4 = *(const int4*)&ibuf[wv][j];
    const float4 w4  = *(const float4*)&wbuf[wv][j];
    outv += w4.x * Vh[(size_t)id4.x * HIDDEN + lane];
    outv += w4.y * Vh[(size_t)id4.y * HIDDEN + lane];
    outv += w4.z * Vh[(size_t)id4.z * HIDDEN + lane];
    outv += w4.w * Vh[(size_t)id4.w * HIDDEN + lane];
  }
  O[(size_t)row * HIDDEN + h * DHEAD + lane] = outv * rz;
}

extern "C" void kernel_launch(void* const* d_in, const int* in_sizes, int n_in,
                              void* d_out, int out_size, void* d_ws, size_t ws_size,
                              hipStream_t stream) {
  const float* x  = (const float*)d_in[0];
  const float* wq = (const float*)d_in[1];
  const float* wk = (const float*)d_in[2];
  const float* wv = (const float*)d_in[3];
  const float* wo = (const float*)d_in[4];
  float* out = (float*)d_out;

  float* Qb = (float*)d_ws;
  float* Kb = Qb + (size_t)S_LEN * HIDDEN;
  float* Vb = Kb + (size_t)S_LEN * HIDDEN;
  float* AO = Vb + (size_t)S_LEN * HIDDEN;
  void*  tail = (void*)(AO + (size_t)S_LEN * HIDDEN);

  const size_t elems = (size_t)NHEAD * S_LEN * S_LEN;
  const size_t base  = (size_t)4 * S_LEN * HIDDEN * 4;        // Q,K,V,AO = 16 MB
  const size_t need_new = base + elems * 4 + elems * 2;       // impu u32 + sch fp16 = 208.25 MB
  const size_t need_r3  = base + (size_t)NHEAD * S_LEN * NSEL * 2 + elems * 4;  // 152.25 MB

  dim3 g(S_LEN / 64, HIDDEN / 64);
  gemm_nt<<<g, 256, 0, stream>>>(x, wq, Qb, S_LEN, HIDDEN, HIDDEN);
  gemm_nt<<<g, 256, 0, stream>>>(x, wk, Kb, S_LEN, HIDDEN, HIDDEN);
  gemm_nt<<<g, 256, 0, stream>>>(x, wv, Vb, S_LEN, HIDDEN, HIDDEN);
  if (ws_size >= need_new) {
    unsigned* impu = (unsigned*)tail;
    _Float16* sch  = (_Float16*)(impu + elems);
    score_gemm<<<dim3(NHEAD * 16 * 32), 256, 0, stream>>>(Qb, Kb, impu, sch);
    fused_select_pv<<<dim3(NHEAD * S_LEN / ROWS_A), 512, 0, stream>>>(impu, sch, Vb, AO);
  } else if (ws_size >= need_r3) {
    unsigned short* selg = (unsigned short*)tail;
    unsigned* impu = (unsigned*)(selg + (size_t)NHEAD * S_LEN * NSEL);
    imp_gemm<<<dim3(NHEAD * 32 * 32), 256, 0, stream>>>(Qb, Kb, impu);
    radix_select<<<dim3(NHEAD * S_LEN / ROWS_A), 512, 0, stream>>>(impu, selg);
    fasa_attend<<<dim3((S_LEN / 4) * NHEAD), 256, 0, stream>>>(Qb, Kb, Vb, selg, AO);
  } else {
    unsigned short* selg = (unsigned short*)tail;
    fasa_select<<<dim3((S_LEN / ROWS_A) * NHEAD), 512, 0, stream>>>(Qb, Kb, selg);
    fasa_attend<<<dim3((S_LEN / 4) * NHEAD), 256, 0, stream>>>(Qb, Kb, Vb, selg, AO);
  }
  gemm_nt<<<g, 256, 0, stream>>>(AO, wo, out, S_LEN, HIDDEN, HIDDEN);
}